// Round 3
// baseline (579.860 us; speedup 1.0000x reference)
//
#include <hip/hip_runtime.h>

// Problem is fixed-shape: B=8192, N=4096, M=4096, G=512, CB=256.
#define B_DIM 8192
#define N_DIM 4096
#define M_DIM 4096
#define G_DIM 512

typedef short bf16x8 __attribute__((ext_vector_type(8)));
typedef float f32x4 __attribute__((ext_vector_type(4)));

typedef __attribute__((address_space(1))) const void gvoid_t;
typedef __attribute__((address_space(3))) void lvoid_t;

__device__ __forceinline__ void load_lds16(const void* g, void* l) {
    __builtin_amdgcn_global_load_lds((gvoid_t*)g, (lvoid_t*)l, 16, 0, 0);
}

// Generic->LDS addrspace cast; as3 pointers are 32-bit LDS byte offsets.
__device__ __forceinline__ unsigned lds_u32(const void* p) {
    return (unsigned)(unsigned long long)(lvoid_t*)p;
}

__device__ __forceinline__ unsigned short f2bf(float f) {
    union { float f; unsigned int u; } v; v.f = f;
    unsigned int u = v.u;
    unsigned int r = (u + 0x7fffu + ((u >> 16) & 1u)) >> 16;
    return (unsigned short)r;
}
__device__ __forceinline__ float bf2f(unsigned short s) {
    union { unsigned int u; float f; } v; v.u = ((unsigned int)s) << 16;
    return v.f;
}

// In-register H16 (unnormalized Hadamard over 16 values).
__device__ __forceinline__ void h16(float* v) {
#pragma unroll
    for (int h = 1; h < 16; h <<= 1) {
#pragma unroll
        for (int i = 0; i < 16; i++) {
            if (!(i & h)) {
                float a = v[i], b = v[i | h];
                v[i] = a + b;
                v[i | h] = a - b;
            }
        }
    }
}

// In-register H64 (unnormalized Hadamard over 64 values).
__device__ __forceinline__ void h64(float* v) {
#pragma unroll
    for (int h = 1; h < 64; h <<= 1) {
#pragma unroll
        for (int i = 0; i < 64; i++) {
            if (!(i & h)) {
                float a = v[i], b = v[i | h];
                v[i] = a + b;
                v[i | h] = a - b;
            }
        }
    }
}

// ---------------------------------------------------------------------------
// Kernel 1: W[m][g*8+j] = (cb1[q1[m][g]][j] + cb2[q2[m][g]][j]*irs) * Wscale
// ---------------------------------------------------------------------------
__global__ __launch_bounds__(256) void k_build_w(
    const int* __restrict__ q1, const int* __restrict__ q2,
    const float* __restrict__ cb1, const float* __restrict__ cb2,
    const float* __restrict__ wsp, const float* __restrict__ irsp,
    unsigned short* __restrict__ W) {
    __shared__ float c1[256 * 9];
    __shared__ float c2[256 * 9];
    int t = threadIdx.x;
#pragma unroll
    for (int j = 0; j < 8; j++) {
        c1[t * 9 + j] = cb1[t * 8 + j];
        c2[t * 9 + j] = cb2[t * 8 + j];
    }
    __syncthreads();
    float ws = wsp[0];
    float irs = irsp[0] * ws;
    int gid = blockIdx.x * 256 + t;  // exact multiple, no guard needed
    int i1 = q1[gid] * 9;
    int i2 = q2[gid] * 9;
    union { unsigned short s[8]; int4 v; } o;
#pragma unroll
    for (int j = 0; j < 8; j++) {
        o.s[j] = f2bf(c1[i1 + j] * ws + c2[i2 + j] * irs);
    }
    *(int4*)(W + (size_t)gid * 8) = o.v;
}

// ---------------------------------------------------------------------------
// Kernel 1b (fused): W'' = (1/64) * (H64_hi (x) H64_lo) over row index m,
// in place, one kernel. Block owns 8 columns x all 4096 rows in f32 LDS.
//
// LDS layout: column-major slabs, f(c, r) = c*4160 + r + (r>>6)
//   (pad 1 float per 64 rows => for r = lo + 64*hi, f = c*4160 + lo + 65*hi).
// Bank math (all free):
//   load/store: lanes stride-1 in r -> stride-1 banks.
//   pass A (over hi, lanes vary lo): stride 4B -> banks 0..63 mod 32, 2-way.
//   pass B (over lo, lanes vary hi): stride 65*4B -> bank stride 1, 2-way.
// Global access: int4 (16B) per lane at 8KB row stride (vs 2B scalar in the
// old two-pass version); one read + one write of W total (vs two of each).
// ---------------------------------------------------------------------------
#define HW_S 4160
__global__ __launch_bounds__(256) void k_hadw2(unsigned short* __restrict__ W) {
    __shared__ float lds[8 * HW_S];  // 133120 B (< 160 KiB)
    int t = threadIdx.x;
    int c0 = blockIdx.x * 8;
    // load: 16 rows per thread, 8 bf16 (int4) each
#pragma unroll
    for (int p = 0; p < 16; p++) {
        int r = t + (p << 8);
        union { int4 v; unsigned short s[8]; } u;
        u.v = *(const int4*)(W + (size_t)r * N_DIM + c0);
        int fr = r + (r >> 6);
#pragma unroll
        for (int c = 0; c < 8; c++) lds[c * HW_S + fr] = bf2f(u.s[c]);
    }
    __syncthreads();
    float v[64];
    // pass A: H64 over hi at fixed (c, lo)
#pragma unroll
    for (int p = 0; p < 2; p++) {
        int idx = t + (p << 8);
        int c = idx >> 6, lo = idx & 63;
        float* base = &lds[c * HW_S + lo];
#pragma unroll
        for (int hi = 0; hi < 64; hi++) v[hi] = base[hi * 65];
        h64(v);
#pragma unroll
        for (int hi = 0; hi < 64; hi++) base[hi * 65] = v[hi];
    }
    __syncthreads();
    // pass B: H64 over lo at fixed (c, hi); 1/64 normalization folded in
#pragma unroll
    for (int p = 0; p < 2; p++) {
        int idx = t + (p << 8);
        int c = idx >> 6, hi = idx & 63;
        float* base = &lds[c * HW_S + hi * 65];
#pragma unroll
        for (int lo = 0; lo < 64; lo++) v[lo] = base[lo];
        h64(v);
#pragma unroll
        for (int lo = 0; lo < 64; lo++) base[lo] = v[lo] * 0.015625f;
    }
    __syncthreads();
    // store
#pragma unroll
    for (int p = 0; p < 16; p++) {
        int r = t + (p << 8);
        int fr = r + (r >> 6);
        union { int4 v; unsigned short s[8]; } u;
#pragma unroll
        for (int c = 0; c < 8; c++) u.s[c] = f2bf(lds[c * HW_S + fr]);
        *(int4*)(W + (size_t)r * N_DIM + c0) = u.v;
    }
}

// ---------------------------------------------------------------------------
// Kernel 2: x_rht = fht(x * SV) -> bf16 (internal GEMM operand).
// ---------------------------------------------------------------------------
__global__ __launch_bounds__(256) void k_rht_in(
    const float* __restrict__ x, const float* __restrict__ SV,
    unsigned short* __restrict__ out) {
    __shared__ float lds[4352];  // f(n) = n + (n>>4), max 4350
    int row = blockIdx.x;
    int t = threadIdx.x;
    const float* xr = x + (size_t)row * N_DIM;
    float v[16];
    // phase A: n = t + 256r
#pragma unroll
    for (int r = 0; r < 16; r++) {
        int n = t + (r << 8);
        v[r] = xr[n] * SV[n] * 0.015625f;
    }
    h16(v);
#pragma unroll
    for (int r = 0; r < 16; r++) { int n = t + (r << 8); lds[n + (n >> 4)] = v[r]; }
    __syncthreads();
    // phase B: n = 16t + r
#pragma unroll
    for (int r = 0; r < 16; r++) { int n = (t << 4) + r; v[r] = lds[n + (n >> 4)]; }
    h16(v);
#pragma unroll
    for (int r = 0; r < 16; r++) { int n = (t << 4) + r; lds[n + (n >> 4)] = v[r]; }
    __syncthreads();
    // phase C: n = (t&15) | (r<<4) | ((t>>4)<<8)
#pragma unroll
    for (int r = 0; r < 16; r++) {
        int n = (t & 15) | (r << 4) | ((t >> 4) << 8);
        v[r] = lds[n + (n >> 4)];
    }
    h16(v);
#pragma unroll
    for (int r = 0; r < 16; r++) {
        int n = (t & 15) | (r << 4) | ((t >> 4) << 8);
        lds[n + (n >> 4)] = v[r];
    }
    __syncthreads();
    unsigned short* orow = out + (size_t)row * N_DIM;
#pragma unroll
    for (int r = 0; r < 16; r++) {
        int n = t + (r << 8);
        orow[n] = f2bf(lds[n + (n >> 4)]);
    }
}

// ---------------------------------------------------------------------------
// Kernel 3: y[b,m] = SU[m] * dot(x_rht[b,:], W''[m,:])   (NT GEMM)
//
// 256x256x(BK=32) tile, 8 waves (2Mx4N), per-wave 128x64, acc[8][4].
// Ring of 4 one-K32-tile LDS buffers (128 KiB), counted vmcnt(8) (never 0).
//
// m201-style PHASE structure (2 phases per K-tile):
//   P1: issue 8 ds_reads (af0-3 + bfr0-3) ; STAGE_A(k+3) ;
//       barrier ; lgkmcnt(0)+SB0 ; setprio(1) 16 MFMA (i=0-3) setprio(0) ;
//       barrier
//   P2: issue 4 ds_reads (af4-7) ; STAGE_B(k+3) ;
//       barrier ; lgkmcnt(0)+SB0 ; setprio(1) 16 MFMA (i=4-7) setprio(0) ;
//       vmcnt(8) ; barrier
// Mechanism (m218b/m252): per-phase barrier pairs + lgkmcnt(0) create wave
// role-split (some waves in MFMA backlog, others in read-drain) -> DS unit
// and MFMA pipes overlap instead of ping-ponging; setprio arbitrates.
//
// Race freedom (same as round-1 verified scheme):
//  - reads of buf[k&3] protected by prev iter's vmcnt(8)+barrier
//    (8 newest outstanding = tiles k+1,k+2 -> tile k landed).
//  - STAGE(k+3) writes buf[(k-1)&3]; tile k-1's reads drained at its own
//    lgkmcnt(0) waits, confirmed for all waves by the k-1 P2-end barrier,
//    which precedes any iter-k stage issue.
// LDS swizzle (rule 21): linear gload_lds dest + inverse-swz SOURCE
// (lx = l ^ (l>>3)) + swz on READ. Measured: 0 bank conflicts.
// XCD swizzle: 512 blocks, each XCD gets 2 bn-columns x 32 bm.
// ---------------------------------------------------------------------------
#define DSR(D, A, OFF) \
    asm volatile("ds_read_b128 %0, %1 offset:" #OFF : "=v"(D) : "v"(A))
#define SB0() __builtin_amdgcn_sched_barrier(0)

__global__ __launch_bounds__(512, 2) void k_gemm(
    const unsigned short* __restrict__ A,   // (B_DIM, N_DIM) bf16
    const unsigned short* __restrict__ Bw,  // (M_DIM, N_DIM) bf16  (= W'')
    const float* __restrict__ SU,
    float* __restrict__ C) {                // (B_DIM, M_DIM) f32
    __shared__ __align__(16) unsigned short lds[4 * 16384];  // 128 KiB

    int t = threadIdx.x;
    int w = t >> 6;   // wave 0..7
    int l = t & 63;

    // XCD-aware tile mapping (bijective, 512 % 8 == 0).
    int lin = blockIdx.x;
    int xcd = lin & 7;
    int idx = lin >> 3;             // 0..63
    int bn = xcd * 2 + (idx >> 5);  // 0..15  (M tiles)
    int bm = idx & 31;              // 0..31  (B tiles)

    // staging: lane l writes LDS slot (row w*16 + l>>2, chunk l&3) of a
    // 128-row half; inverse-swizzled global source uses lx = l ^ (l>>3).
    int lx = l ^ (l >> 3);
    const unsigned short* aS0 =
        A + (size_t)(bm * 256 + w * 16 + (lx >> 2)) * N_DIM + (lx & 3) * 8;
    const unsigned short* aS1 = aS0 + (size_t)128 * N_DIM;
    const unsigned short* bS0 =
        Bw + (size_t)(bn * 256 + w * 16 + (lx >> 2)) * N_DIM + (lx & 3) * 8;
    const unsigned short* bS1 = bS0 + (size_t)128 * N_DIM;

    // fragment read addresses (swizzled)
    int wm = w >> 2;   // 0..1  (M half)
    int wn = w & 3;    // 0..3  (N quarter)
    int quad = l >> 4;
    int ln = l & 15;
    unsigned ldsU = lds_u32(lds);
    unsigned aBase = ldsU +
        (unsigned)(((((wm * 128) + ln) << 6) | (quad << 4)) ^ ((ln >> 1) << 4));
    unsigned bBase = ldsU + 16384u +
        (unsigned)(((((wn * 64) + ln) << 6) | (quad << 4)) ^ ((ln >> 1) << 4));

    f32x4 acc[8][4];
#pragma unroll
    for (int i = 0; i < 8; i++)
#pragma unroll
        for (int j = 0; j < 4; j++) {
            f32x4 z = {0.f, 0.f, 0.f, 0.f};
            acc[i][j] = z;
        }

#define STAGE_A(KT) do {                                            \
        int kt_ = (KT);                                             \
        int ks_ = kt_ < 127 ? kt_ : 127;                            \
        unsigned short* d_ = lds + ((unsigned)kt_ & 3u) * 16384 + w * 512; \
        load_lds16(aS0 + ks_ * 32, d_);                             \
        load_lds16(aS1 + ks_ * 32, d_ + 4096);                      \
    } while (0)
#define STAGE_B(KT) do {                                            \
        int kt_ = (KT);                                             \
        int ks_ = kt_ < 127 ? kt_ : 127;                            \
        unsigned short* d_ = lds + ((unsigned)kt_ & 3u) * 16384 + w * 512; \
        load_lds16(bS0 + ks_ * 32, d_ + 8192);                      \
        load_lds16(bS1 + ks_ * 32, d_ + 12288);                     \
    } while (0)

#define GROUP(I) do {                                               \
        acc[I][0] = __builtin_amdgcn_mfma_f32_16x16x32_bf16(        \
            af[I], bfr[0], acc[I][0], 0, 0, 0);                     \
        acc[I][1] = __builtin_amdgcn_mfma_f32_16x16x32_bf16(        \
            af[I], bfr[1], acc[I][1], 0, 0, 0);                     \
        acc[I][2] = __builtin_amdgcn_mfma_f32_16x16x32_bf16(        \
            af[I], bfr[2], acc[I][2], 0, 0, 0);                     \
        acc[I][3] = __builtin_amdgcn_mfma_f32_16x16x32_bf16(        \
            af[I], bfr[3], acc[I][3], 0, 0, 0);                     \
    } while (0)

    STAGE_A(0); STAGE_B(0);
    STAGE_A(1); STAGE_B(1);
    STAGE_A(2); STAGE_B(2);
    asm volatile("s_waitcnt vmcnt(8)");  // tile 0 landed (1,2 in flight)
    __builtin_amdgcn_s_barrier();

    bf16x8 af[8], bfr[4];
    for (int k = 0; k < N_DIM / 32; k++) {
        unsigned au = aBase + (unsigned)(k & 3) * 32768u;
        unsigned bu = bBase + (unsigned)(k & 3) * 32768u;
        // ---- phase 1 ----
        DSR(af[0], au, 0);
        DSR(af[1], au, 1024);
        DSR(af[2], au, 2048);
        DSR(af[3], au, 3072);
        DSR(bfr[0], bu, 0);
        DSR(bfr[1], bu, 1024);
        DSR(bfr[2], bu, 2048);
        DSR(bfr[3], bu, 3072);
        STAGE_A(k + 3);
        __builtin_amdgcn_s_barrier();
        asm volatile("s_waitcnt lgkmcnt(0)");
        SB0();  // rule 18: keep MFMAs below the wait
        __builtin_amdgcn_s_setprio(1);
        GROUP(0); GROUP(1); GROUP(2); GROUP(3);
        __builtin_amdgcn_s_setprio(0);
        __builtin_amdgcn_s_barrier();
        // ---- phase 2 ----
        DSR(af[4], au, 4096);
        DSR(af[5], au, 5120);
        DSR(af[6], au, 6144);
        DSR(af[7], au, 7168);
        STAGE_B(k + 3);
        __builtin_amdgcn_s_barrier();
        asm volatile("s_waitcnt lgkmcnt(0)");
        SB0();
        __builtin_amdgcn_s_setprio(1);
        GROUP(4); GROUP(5); GROUP(6); GROUP(7);
        __builtin_amdgcn_s_setprio(0);
        asm volatile("s_waitcnt vmcnt(8)");  // tile k+1 landed; never 0
        __builtin_amdgcn_s_barrier();
    }
    asm volatile("s_waitcnt vmcnt(0) lgkmcnt(0)");  // drain tail dummies

    // epilogue: C/D layout col=lane&15, row=quad*4+reg (m89/m91-verified)
#pragma unroll
    for (int j = 0; j < 4; j++) {
        int col = bn * 256 + wn * 64 + j * 16 + ln;
        float su = SU[col];
#pragma unroll
        for (int i = 0; i < 8; i++) {
#pragma unroll
            for (int r = 0; r < 4; r++) {
                int rowg = bm * 256 + wm * 128 + i * 16 + quad * 4 + r;
                C[(size_t)rowg * M_DIM + col] = acc[i][j][r] * su;
            }
        }
    }
#undef STAGE_A
#undef STAGE_B
#undef GROUP
}

extern "C" void kernel_launch(void* const* d_in, const int* in_sizes, int n_in,
                              void* d_out, int out_size, void* d_ws, size_t ws_size,
                              hipStream_t stream) {
    const float* x    = (const float*)d_in[0];
    const int*   q1   = (const int*)d_in[1];
    const int*   q2   = (const int*)d_in[2];
    const float* SU   = (const float*)d_in[3];
    const float* SV   = (const float*)d_in[4];
    const float* cb1  = (const float*)d_in[5];
    const float* cb2  = (const float*)d_in[6];
    const float* wsp  = (const float*)d_in[7];
    const float* irsp = (const float*)d_in[8];
    float* out = (float*)d_out;  // reference output dtype: float32

    // workspace: x_rht bf16 (64MiB) | W bf16 (32MiB)  => 96MiB total
    unsigned short* xrht = (unsigned short*)d_ws;
    unsigned short* Wb   = xrht + (size_t)B_DIM * N_DIM;

    k_build_w<<<dim3((M_DIM * G_DIM) / 256), dim3(256), 0, stream>>>(
        q1, q2, cb1, cb2, wsp, irsp, Wb);
    // W'' = (1/64) H_4096 W  (fused column-direction Hadamard, one pass)
    k_hadw2<<<dim3(N_DIM / 8), dim3(256), 0, stream>>>(Wb);
    k_rht_in<<<dim3(B_DIM), dim3(256), 0, stream>>>(x, SV, xrht);
    k_gemm<<<dim3(512), dim3(512), 0, stream>>>(xrht, Wb, SU, out);
}

// Round 4
// 534.198 us; speedup vs baseline: 1.0855x; 1.0855x over previous
//
#include <hip/hip_runtime.h>

// Problem is fixed-shape: B=8192, N=4096, M=4096, G=512, CB=256.
#define B_DIM 8192
#define N_DIM 4096
#define M_DIM 4096
#define G_DIM 512

typedef short bf16x8 __attribute__((ext_vector_type(8)));
typedef float f32x4 __attribute__((ext_vector_type(4)));

typedef __attribute__((address_space(1))) const void gvoid_t;
typedef __attribute__((address_space(3))) void lvoid_t;

__device__ __forceinline__ void load_lds16(const void* g, void* l) {
    __builtin_amdgcn_global_load_lds((gvoid_t*)g, (lvoid_t*)l, 16, 0, 0);
}

__device__ __forceinline__ unsigned short f2bf(float f) {
    union { float f; unsigned int u; } v; v.f = f;
    unsigned int u = v.u;
    unsigned int r = (u + 0x7fffu + ((u >> 16) & 1u)) >> 16;
    return (unsigned short)r;
}
__device__ __forceinline__ float bf2f(unsigned short s) {
    union { unsigned int u; float f; } v; v.u = ((unsigned int)s) << 16;
    return v.f;
}

// In-register H16 (unnormalized Hadamard over 16 values).
__device__ __forceinline__ void h16(float* v) {
#pragma unroll
    for (int h = 1; h < 16; h <<= 1) {
#pragma unroll
        for (int i = 0; i < 16; i++) {
            if (!(i & h)) {
                float a = v[i], b = v[i | h];
                v[i] = a + b;
                v[i | h] = a - b;
            }
        }
    }
}

// In-register H64 (unnormalized Hadamard over 64 values).
__device__ __forceinline__ void h64(float* v) {
#pragma unroll
    for (int h = 1; h < 64; h <<= 1) {
#pragma unroll
        for (int i = 0; i < 64; i++) {
            if (!(i & h)) {
                float a = v[i], b = v[i | h];
                v[i] = a + b;
                v[i | h] = a - b;
            }
        }
    }
}

// ---------------------------------------------------------------------------
// Kernel 1: W[m][g*8+j] = (cb1[q1[m][g]][j] + cb2[q2[m][g]][j]*irs) * Wscale
// ---------------------------------------------------------------------------
__global__ __launch_bounds__(256) void k_build_w(
    const int* __restrict__ q1, const int* __restrict__ q2,
    const float* __restrict__ cb1, const float* __restrict__ cb2,
    const float* __restrict__ wsp, const float* __restrict__ irsp,
    unsigned short* __restrict__ W) {
    __shared__ float c1[256 * 9];
    __shared__ float c2[256 * 9];
    int t = threadIdx.x;
#pragma unroll
    for (int j = 0; j < 8; j++) {
        c1[t * 9 + j] = cb1[t * 8 + j];
        c2[t * 9 + j] = cb2[t * 8 + j];
    }
    __syncthreads();
    float ws = wsp[0];
    float irs = irsp[0] * ws;
    int gid = blockIdx.x * 256 + t;  // exact multiple, no guard needed
    int i1 = q1[gid] * 9;
    int i2 = q2[gid] * 9;
    union { unsigned short s[8]; int4 v; } o;
#pragma unroll
    for (int j = 0; j < 8; j++) {
        o.s[j] = f2bf(c1[i1 + j] * ws + c2[i2 + j] * irs);
    }
    *(int4*)(W + (size_t)gid * 8) = o.v;
}

// ---------------------------------------------------------------------------
// Kernel 1b: column-direction Hadamard on W (in place, bf16). Two passes
// (known-good round-1 config; fused LDS version regressed: uncoalesced rows).
//   pass1: base_mul=1,  step=64, scale=1        (transform over hi)
//   pass2: base_mul=64, step=1,  scale=1/64     (transform over lo)
// Lanes read consecutive columns -> coalesced 512B/wave-instr.
// ---------------------------------------------------------------------------
__global__ __launch_bounds__(256) void k_hadw(
    unsigned short* __restrict__ W, int base_mul, int step, float scale) {
    int c = blockIdx.x * 256 + threadIdx.x;
    int base = blockIdx.y * base_mul;
    float v[64];
#pragma unroll
    for (int j = 0; j < 64; j++)
        v[j] = bf2f(W[(size_t)(base + j * step) * N_DIM + c]);
    h64(v);
#pragma unroll
    for (int j = 0; j < 64; j++)
        W[(size_t)(base + j * step) * N_DIM + c] = f2bf(v[j] * scale);
}

// ---------------------------------------------------------------------------
// Kernel 2 (v2): x_rht = fht(x * SV) -> bf16. One WAVE (64 threads) per row.
// H4096 = H16(n2) x H16(n1) x H16(n0) over base-16 digits of n.
// Lane u owns 4 complete n2-classes (c = 4u..4u+3) -> float4 global loads
// (16B/lane, fully coalesced 1KB/wave-instr), short8 stores (16B/lane).
// LDS pad f(n) = n + (n>>4); bank math: every phase <=2 lanes/bank (free).
// ---------------------------------------------------------------------------
__global__ __launch_bounds__(64) void k_rht_in(
    const float* __restrict__ x, const float* __restrict__ SV,
    unsigned short* __restrict__ out) {
    __shared__ float lds[4352];  // f(n) max 4350
    int u = threadIdx.x;  // 0..63
    int row = blockIdx.x;
    const float* xr = x + (size_t)row * N_DIM;
    float v[4][16];
    // phase A: transform over n2 (=r) at fixed class c = n&255 = 4u+i
#pragma unroll
    for (int r = 0; r < 16; r++) {
        int n = 4 * u + (r << 8);
        float4 a = *(const float4*)(xr + n);
        float4 s = *(const float4*)(SV + n);
        v[0][r] = a.x * s.x * 0.015625f;
        v[1][r] = a.y * s.y * 0.015625f;
        v[2][r] = a.z * s.z * 0.015625f;
        v[3][r] = a.w * s.w * 0.015625f;
    }
#pragma unroll
    for (int i = 0; i < 4; i++) h16(v[i]);
#pragma unroll
    for (int r = 0; r < 16; r++) {
#pragma unroll
        for (int i = 0; i < 4; i++) {
            int n = (r << 8) + 4 * u + i;
            lds[n + (n >> 4)] = v[i][r];
        }
    }
    __syncthreads();
    // phase B: transform over n0 at fixed g = n>>4; lane u: g = u + 64j.
    // idx = 17g + n0 (contiguous 16 within a group).
#pragma unroll
    for (int j = 0; j < 4; j++) {
        int base = 17 * (u + (j << 6));
        float w[16];
#pragma unroll
        for (int n0 = 0; n0 < 16; n0++) w[n0] = lds[base + n0];
        h16(w);
#pragma unroll
        for (int n0 = 0; n0 < 16; n0++) lds[base + n0] = w[n0];
    }
    __syncthreads();
    // phase C: transform over n1 (=r) at fixed (n2, n0);
    // n2 = (u>>4)+4j, n0 = u&15; idx = 272*n2 + 17*r + n0.
#pragma unroll
    for (int j = 0; j < 4; j++) {
        int base = 272 * ((u >> 4) + (j << 2)) + (u & 15);
        float w[16];
#pragma unroll
        for (int r = 0; r < 16; r++) w[r] = lds[base + 17 * r];
        h16(w);
#pragma unroll
        for (int r = 0; r < 16; r++) lds[base + 17 * r] = w[r];
    }
    __syncthreads();
    // store: lane u writes 8 contiguous bf16 at n = 8u + 512s (short8).
    unsigned short* orow = out + (size_t)row * N_DIM;
#pragma unroll
    for (int s = 0; s < 8; s++) {
        int n = 8 * u + (s << 9);
        union { unsigned short h[8]; int4 q; } o;
#pragma unroll
        for (int jj = 0; jj < 8; jj++) {
            int nn = n + jj;
            o.h[jj] = f2bf(lds[nn + (nn >> 4)]);
        }
        *(int4*)(orow + n) = o.q;
    }
}

// ---------------------------------------------------------------------------
// Kernel 3: y[b,m] = SU[m] * dot(x_rht[b,:], W''[m,:])   (NT GEMM)
//
// 256x256x(BK=32) tile, 8 waves (2Mx4N), per-wave 128x64, acc[8][4].
// Ring of 4 one-K32-tile LDS buffers (128 KiB), counted vmcnt(8) (never 0).
//
// v4: COMPILER-SCHEDULED LDS reads (plain C++ derefs). Rounds 1-3 showed all
// manual wait structures (lgkm(0) wall / progressive lgkm+SB0 / barrier-pair
// phases) serialize DS-drain -> MFMA in lockstep (T_iter ~2475-2680 cy vs
// DS floor ~1400). m97 evidence: hipcc emits fine-grained lgkmcnt(4/3/1/0)
// between C++ ds_reads and MFMAs -> per-wave DS/MFMA interleave without
// rigid walls. We keep only the structurally required asm:
//   - vmcnt(8) + s_barrier per iteration (counted prefetch, never drains 0)
//   - lgkmcnt(0) before the barrier (race proof: all ds_reads of buf[k&3]
//     complete before any wave can issue STAGE(k+4) overwriting it; this
//     wait is free since all reads were already consumed by MFMAs)
//   - "memory" fences so C++ LDS reads can't hoist across the barrier
// LDS swizzle (rule 21): linear gload_lds dest + inverse-swz SOURCE
// (lx = l ^ (l>>3)) + swz on READ. Measured: 0 bank conflicts.
// XCD swizzle: 512 blocks, each XCD gets 2 bn-columns x 32 bm.
// ---------------------------------------------------------------------------
__global__ __launch_bounds__(512, 2) void k_gemm(
    const unsigned short* __restrict__ A,   // (B_DIM, N_DIM) bf16
    const unsigned short* __restrict__ Bw,  // (M_DIM, N_DIM) bf16  (= W'')
    const float* __restrict__ SU,
    float* __restrict__ C) {                // (B_DIM, M_DIM) f32
    __shared__ __align__(16) unsigned short lds[4 * 16384];  // 128 KiB

    int t = threadIdx.x;
    int w = t >> 6;   // wave 0..7
    int l = t & 63;

    // XCD-aware tile mapping (bijective, 512 % 8 == 0).
    int lin = blockIdx.x;
    int xcd = lin & 7;
    int idx = lin >> 3;             // 0..63
    int bn = xcd * 2 + (idx >> 5);  // 0..15  (M tiles)
    int bm = idx & 31;              // 0..31  (B tiles)

    // staging: lane l writes LDS slot (row w*16 + l>>2, chunk l&3) of a
    // 128-row half; inverse-swizzled global source uses lx = l ^ (l>>3).
    int lx = l ^ (l >> 3);
    const unsigned short* aS0 =
        A + (size_t)(bm * 256 + w * 16 + (lx >> 2)) * N_DIM + (lx & 3) * 8;
    const unsigned short* aS1 = aS0 + (size_t)128 * N_DIM;
    const unsigned short* bS0 =
        Bw + (size_t)(bn * 256 + w * 16 + (lx >> 2)) * N_DIM + (lx & 3) * 8;
    const unsigned short* bS1 = bS0 + (size_t)128 * N_DIM;

    // fragment read offsets (elements, swizzled; byte offsets all 16B-aligned)
    int wm = w >> 2;   // 0..1  (M half)
    int wn = w & 3;    // 0..3  (N quarter)
    int quad = l >> 4;
    int ln = l & 15;
    unsigned aOff =
        (unsigned)((((wm * 128 + ln) << 6) | (quad << 4)) ^ ((ln >> 1) << 4)) >> 1;
    unsigned bOff = 8192u +
        ((unsigned)((((wn * 64 + ln) << 6) | (quad << 4)) ^ ((ln >> 1) << 4)) >> 1);

    f32x4 acc[8][4];
#pragma unroll
    for (int i = 0; i < 8; i++)
#pragma unroll
        for (int j = 0; j < 4; j++) {
            f32x4 z = {0.f, 0.f, 0.f, 0.f};
            acc[i][j] = z;
        }

#define STAGE(KT) do {                                              \
        int kt_ = (KT);                                             \
        int ks_ = kt_ < 127 ? kt_ : 127;                            \
        unsigned short* d_ = lds + ((unsigned)kt_ & 3u) * 16384 + w * 512; \
        load_lds16(aS0 + ks_ * 32, d_);                             \
        load_lds16(aS1 + ks_ * 32, d_ + 4096);                      \
        load_lds16(bS0 + ks_ * 32, d_ + 8192);                      \
        load_lds16(bS1 + ks_ * 32, d_ + 12288);                     \
    } while (0)

    STAGE(0);
    STAGE(1);
    STAGE(2);
    asm volatile("s_waitcnt vmcnt(8)");  // tile 0 landed (1,2 in flight)
    __builtin_amdgcn_s_barrier();
    asm volatile("" ::: "memory");

    for (int k = 0; k < N_DIM / 32; k++) {
        STAGE(k + 3);  // writes buf[(k-1)&3]; its reads drained pre-barrier

        const unsigned short* aP = lds + ((unsigned)k & 3u) * 16384u + aOff;
        const unsigned short* bP = lds + ((unsigned)k & 3u) * 16384u + bOff;
        bf16x8 af[8], bfr[4];
#pragma unroll
        for (int j = 0; j < 4; j++) bfr[j] = *(const bf16x8*)(bP + j * 512);
#pragma unroll
        for (int i = 0; i < 8; i++) af[i] = *(const bf16x8*)(aP + i * 512);
#pragma unroll
        for (int i = 0; i < 8; i++)
#pragma unroll
            for (int j = 0; j < 4; j++)
                acc[i][j] = __builtin_amdgcn_mfma_f32_16x16x32_bf16(
                    af[i], bfr[j], acc[i][j], 0, 0, 0);

        asm volatile("s_waitcnt lgkmcnt(0)" ::: "memory");  // reads drained
        asm volatile("s_waitcnt vmcnt(8)");  // tile k+1 landed; never 0
        __builtin_amdgcn_s_barrier();
        asm volatile("" ::: "memory");
    }
    asm volatile("s_waitcnt vmcnt(0)");  // drain tail dummy stages

    // epilogue: C/D layout col=lane&15, row=quad*4+reg (m89/m91-verified)
#pragma unroll
    for (int j = 0; j < 4; j++) {
        int col = bn * 256 + wn * 64 + j * 16 + ln;
        float su = SU[col];
#pragma unroll
        for (int i = 0; i < 8; i++) {
#pragma unroll
            for (int r = 0; r < 4; r++) {
                int rowg = bm * 256 + wm * 128 + i * 16 + quad * 4 + r;
                C[(size_t)rowg * M_DIM + col] = acc[i][j][r] * su;
            }
        }
    }
#undef STAGE
}

extern "C" void kernel_launch(void* const* d_in, const int* in_sizes, int n_in,
                              void* d_out, int out_size, void* d_ws, size_t ws_size,
                              hipStream_t stream) {
    const float* x    = (const float*)d_in[0];
    const int*   q1   = (const int*)d_in[1];
    const int*   q2   = (const int*)d_in[2];
    const float* SU   = (const float*)d_in[3];
    const float* SV   = (const float*)d_in[4];
    const float* cb1  = (const float*)d_in[5];
    const float* cb2  = (const float*)d_in[6];
    const float* wsp  = (const float*)d_in[7];
    const float* irsp = (const float*)d_in[8];
    float* out = (float*)d_out;  // reference output dtype: float32

    // workspace: x_rht bf16 (64MiB) | W bf16 (32MiB)  => 96MiB total
    unsigned short* xrht = (unsigned short*)d_ws;
    unsigned short* Wb   = xrht + (size_t)B_DIM * N_DIM;

    k_build_w<<<dim3((M_DIM * G_DIM) / 256), dim3(256), 0, stream>>>(
        q1, q2, cb1, cb2, wsp, irsp, Wb);
    // W'' = (1/64) H_4096 W  (column-direction Hadamard, two H64 passes)
    k_hadw<<<dim3(N_DIM / 256, 64), dim3(256), 0, stream>>>(Wb, 1, 64, 1.0f);
    k_hadw<<<dim3(N_DIM / 256, 64), dim3(256), 0, stream>>>(Wb, 64, 1, 0.015625f);
    k_rht_in<<<dim3(B_DIM), dim3(64), 0, stream>>>(x, SV, xrht);
    k_gemm<<<dim3(512), dim3(512), 0, stream>>>(xrht, Wb, SU, out);
}